// Round 1
// baseline (41576.694 us; speedup 1.0000x reference)
//
#include <hip/hip_runtime.h>
#include <hip/hip_bf16.h>

#define T_TOT 65536
#define DN 302
#define DIN 306
#define L2E 1.4426950408889634f
#define S2E 2.8853900817779268f

typedef float v2f __attribute__((ext_vector_type(2)));
typedef float v4f __attribute__((ext_vector_type(4)));

// ---------------------------------------------------------------------------
// prep: build merged/scaled weights + transposed input GEMM weight
//   W_big [3][64][64] (g, j, l): g0 = L2E*(W_hh_r + W_ihb_r@W_out)
//                               g1 = L2E*(W_hh_z + W_ihb_z@W_out)
//                               g2 = S2E* W_hh_n
//   Wibn  [4][64]: S2E * W_ihb(n rows), k-major lane-fastest
//   cvec  [192]: scale*(b_ih + (rz? b_hh) + W_ihb@b_out)
//   W_T   [302][192]: W_ih neural part transposed
// ---------------------------------------------------------------------------
__global__ void prep_kernel(const float* __restrict__ W_ih, const float* __restrict__ W_hh,
                            const float* __restrict__ b_ih, const float* __restrict__ b_hh,
                            const float* __restrict__ W_out, const float* __restrict__ b_out,
                            float* __restrict__ W_big, float* __restrict__ Wibn,
                            float* __restrict__ cvec, float* __restrict__ W_T)
{
    int idx = blockIdx.x * 256 + threadIdx.x;
    if (idx < 12288) {
        int g = idx >> 12;
        int j = (idx >> 6) & 63;
        int l = idx & 63;
        float v;
        if (g < 2) {
            int i = g * 64 + l;
            float acc = W_hh[i * 64 + j];
            #pragma unroll
            for (int k = 0; k < 4; k++)
                acc = fmaf(W_ih[i * DIN + DN + k], W_out[k * 64 + j], acc);
            v = L2E * acc;
        } else {
            int i = 128 + l;
            v = S2E * W_hh[i * 64 + j];
        }
        W_big[idx] = v;
    } else if (idx < 12544) {            // 12288 + 256
        int r = idx - 12288;
        int k = r >> 6, l = r & 63;
        Wibn[r] = S2E * W_ih[(128 + l) * DIN + DN + k];
    } else if (idx < 12736) {            // + 192
        int i = idx - 12544;
        float acc = b_ih[i] + (i < 128 ? b_hh[i] : 0.f);
        #pragma unroll
        for (int k = 0; k < 4; k++)
            acc = fmaf(W_ih[i * DIN + DN + k], b_out[k], acc);
        cvec[i] = ((i < 128) ? L2E : S2E) * acc;
    } else if (idx < 12736 + 57984) {    // 302*192
        int r = idx - 12736;             // r = k*192 + c
        int k = r / 192;
        int c = r - k * 192;
        W_T[r] = W_ih[c * DIN + k];
    }
}

// ---------------------------------------------------------------------------
// A: gi4[t][l][{r,z,n,pad}] = scale * (W_ihn @ neural_t) + cvec   (T x 64 x 4)
// ---------------------------------------------------------------------------
__global__ void gi_gemm(const float* __restrict__ neural, const float* __restrict__ W_T,
                        const float* __restrict__ cvec, float* __restrict__ gi4)
{
    int c = threadIdx.x;                 // 0..191
    size_t t0 = (size_t)blockIdx.x * 8;
    float acc[8];
    #pragma unroll
    for (int q = 0; q < 8; q++) acc[q] = 0.f;
    const float* nptr = neural + t0 * DN;
    for (int k = 0; k < DN; k++) {
        float w = W_T[k * 192 + c];
        #pragma unroll
        for (int q = 0; q < 8; q++)
            acc[q] = fmaf(w, nptr[(size_t)q * DN + k], acc[q]);
    }
    float s  = (c < 128) ? L2E : S2E;
    float cv = cvec[c];
    int lo = c & 63, g = c >> 6;
    #pragma unroll
    for (int q = 0; q < 8; q++)
        gi4[(t0 + q) * 256 + lo * 4 + g] = fmaf(s, acc[q], cv);
}

// ---------------------------------------------------------------------------
// B: explicit warmup steps t = 0,1,2 (GT feedback), writes h_all rows 0..2
// ---------------------------------------------------------------------------
__global__ void gru_warm(const float* __restrict__ W_ih, const float* __restrict__ W_hh,
                         const float* __restrict__ b_hh, const float* __restrict__ b_gt,
                         const float* __restrict__ b_out, const float* __restrict__ gi4,
                         float* __restrict__ h_all)
{
    int l = threadIdx.x;
    __shared__ __align__(16) float hs[64];
    float wibr[4], wibz[4], wibn[4];
    #pragma unroll
    for (int k = 0; k < 4; k++) {
        wibr[k] = W_ih[l * DIN + DN + k];
        wibz[k] = W_ih[(64 + l) * DIN + DN + k];
        wibn[k] = W_ih[(128 + l) * DIN + DN + k];
    }
    float bhn = b_hh[128 + l];
    float h = 0.f;
    hs[l] = 0.f;
    for (int t = 0; t < 3; t++) {
        const float* bin = (t < 2) ? b_gt : (b_gt + 4);
        v4f g = *(const v4f*)(gi4 + (size_t)t * 256 + l * 4);
        float dr = 0.f, dz = 0.f, dn = 0.f;
        #pragma unroll
        for (int k = 0; k < 4; k++) {
            float d = bin[k] - b_out[k];
            dr = fmaf(wibr[k], d, dr);
            dz = fmaf(wibz[k], d, dz);
            dn = fmaf(wibn[k], d, dn);
        }
        float ur = g.x + L2E * dr, uz = g.y + L2E * dz, un_i = g.z + S2E * dn;
        float ar = 0.f, az = 0.f, anh = bhn;
        for (int j = 0; j < 64; j++) {
            float hj = hs[j];
            ar  = fmaf(W_hh[l * 64 + j],         hj, ar);
            az  = fmaf(W_hh[(64 + l) * 64 + j],  hj, az);
            anh = fmaf(W_hh[(128 + l) * 64 + j], hj, anh);
        }
        ur += L2E * ar;
        uz += L2E * az;
        float r = __builtin_amdgcn_rcpf(1.f + __builtin_amdgcn_exp2f(-ur));
        float z = __builtin_amdgcn_rcpf(1.f + __builtin_amdgcn_exp2f(-uz));
        float un = fmaf(r, S2E * anh, un_i);
        float e2 = __builtin_amdgcn_exp2f(un);
        float nn = fmaf(-2.f, __builtin_amdgcn_rcpf(e2 + 1.f), 1.f);
        h = nn + z * (h - nn);
        h_all[(size_t)t * 64 + l] = h;
        hs[l] = h;   // single wave, lockstep: all reads above already done
    }
}

// ---------------------------------------------------------------------------
// C: main sequential recurrence, t = 3..65535, single wave, weights in VGPRs
// ---------------------------------------------------------------------------
__global__ __launch_bounds__(64, 1) void gru_main(
    const float* __restrict__ W_big, const float* __restrict__ Wibn,
    const float* __restrict__ W_out, const float* __restrict__ b_hh,
    const float* __restrict__ gi4, float* __restrict__ h_all)
{
    const int l = threadIdx.x;
    __shared__ __align__(16) float hs[64];

    v2f wr[32], wz[32], wn[32];
    #pragma unroll
    for (int j = 0; j < 32; j++) {
        wr[j] = v2f{W_big[(2 * j) * 64 + l],         W_big[(2 * j + 1) * 64 + l]};
        wz[j] = v2f{W_big[(64 + 2 * j) * 64 + l],    W_big[(64 + 2 * j + 1) * 64 + l]};
        wn[j] = v2f{W_big[(128 + 2 * j) * 64 + l],   W_big[(128 + 2 * j + 1) * 64 + l]};
    }
    float wib0 = Wibn[l], wib1 = Wibn[64 + l], wib2 = Wibn[128 + l], wib3 = Wibn[192 + l];
    float wo0 = W_out[l], wo1 = W_out[64 + l], wo2 = W_out[128 + l], wo3 = W_out[192 + l];
    const float bhn_s = S2E * b_hh[128 + l];

    float h = h_all[2 * 64 + l];
    hs[l] = h;

    // initial corr = S2E * W_ihb_n @ (W_out @ h_2)
    float p0 = wo0 * h, p1 = wo1 * h, p2 = wo2 * h, p3 = wo3 * h;
    #pragma unroll
    for (int m = 32; m >= 1; m >>= 1) {
        p0 += __shfl_xor(p0, m, 64);
        p1 += __shfl_xor(p1, m, 64);
        p2 += __shfl_xor(p2, m, 64);
        p3 += __shfl_xor(p3, m, 64);
    }
    float corr = wib0 * p0 + wib1 * p1 + wib2 * p2 + wib3 * p3;

    auto step = [&](v4f g, int t) {
        v2f z2 = v2f{0.f, 0.f};
        v2f ar0 = z2, ar1 = z2, az0 = z2, az1 = z2, an1 = z2;
        v2f an0 = v2f{bhn_s, 0.f};
        #pragma unroll
        for (int jc = 0; jc < 16; jc++) {
            v4f hv = *(const v4f*)(hs + 4 * jc);
            v2f h01 = v2f{hv.x, hv.y}, h23 = v2f{hv.z, hv.w};
            ar0 = __builtin_elementwise_fma(wr[2 * jc],     h01, ar0);
            ar1 = __builtin_elementwise_fma(wr[2 * jc + 1], h23, ar1);
            az0 = __builtin_elementwise_fma(wz[2 * jc],     h01, az0);
            az1 = __builtin_elementwise_fma(wz[2 * jc + 1], h23, az1);
            an0 = __builtin_elementwise_fma(wn[2 * jc],     h01, an0);
            an1 = __builtin_elementwise_fma(wn[2 * jc + 1], h23, an1);
        }
        v2f ars = ar0 + ar1, azs = az0 + az1, ans = an0 + an1;
        float ar = ars.x + ars.y, az = azs.x + azs.y, an = ans.x + ans.y;
        float ur = g.x + ar, uz = g.y + az;
        float r = __builtin_amdgcn_rcpf(1.f + __builtin_amdgcn_exp2f(-ur));
        float z = __builtin_amdgcn_rcpf(1.f + __builtin_amdgcn_exp2f(-uz));
        float un = g.z + corr + r * an;
        float e2 = __builtin_amdgcn_exp2f(un);
        float nn = fmaf(-2.f, __builtin_amdgcn_rcpf(e2 + 1.f), 1.f);
        h = nn + z * (h - nn);
        h_all[(size_t)t * 64 + l] = h;
        hs[l] = h;   // after all reads this step (lockstep single wave)
        float q0 = wo0 * h, q1 = wo1 * h, q2 = wo2 * h, q3 = wo3 * h;
        #pragma unroll
        for (int m = 32; m >= 1; m >>= 1) {
            q0 += __shfl_xor(q0, m, 64);
            q1 += __shfl_xor(q1, m, 64);
            q2 += __shfl_xor(q2, m, 64);
            q3 += __shfl_xor(q3, m, 64);
        }
        corr = wib0 * q0 + wib1 * q1 + wib2 * q2 + wib3 * q3;
    };

    const v4f* gp = (const v4f*)gi4;
    v4f gA = gp[(size_t)3 * 64 + l];
    v4f gB = gp[(size_t)4 * 64 + l];
    for (int t = 3; t < 65535; t += 2) {
        int t2 = (t + 2 < T_TOT) ? t + 2 : T_TOT - 1;
        int t3 = (t + 3 < T_TOT) ? t + 3 : T_TOT - 1;
        v4f gC = gp[(size_t)t2 * 64 + l];   // prefetch 2 steps ahead
        v4f gD = gp[(size_t)t3 * 64 + l];
        step(gA, t);
        step(gB, t + 1);
        gA = gC;
        gB = gD;
    }
    step(gA, T_TOT - 1);
}

// ---------------------------------------------------------------------------
// D: preds = h_all @ W_out^T + b_out
// ---------------------------------------------------------------------------
__global__ void readout(const float* __restrict__ h_all, const float* __restrict__ W_out,
                        const float* __restrict__ b_out, float* __restrict__ preds)
{
    int t = blockIdx.x * 256 + threadIdx.x;
    v4f acc = v4f{b_out[0], b_out[1], b_out[2], b_out[3]};
    const v4f* hp = (const v4f*)(h_all + (size_t)t * 64);
    #pragma unroll
    for (int jc = 0; jc < 16; jc++) {
        v4f hv = hp[jc];
        #pragma unroll
        for (int e = 0; e < 4; e++) {
            float hvv = hv[e];
            int j = jc * 4 + e;
            acc.x = fmaf(W_out[j],       hvv, acc.x);
            acc.y = fmaf(W_out[64 + j],  hvv, acc.y);
            acc.z = fmaf(W_out[128 + j], hvv, acc.z);
            acc.w = fmaf(W_out[192 + j], hvv, acc.w);
        }
    }
    *(v4f*)(preds + (size_t)t * 4) = acc;
}

// ---------------------------------------------------------------------------
extern "C" void kernel_launch(void* const* d_in, const int* in_sizes, int n_in,
                              void* d_out, int out_size, void* d_ws, size_t ws_size,
                              hipStream_t stream)
{
    const float* neural = (const float*)d_in[0];
    const float* b_gt   = (const float*)d_in[1];
    const float* W_ih   = (const float*)d_in[2];
    const float* W_hh   = (const float*)d_in[3];
    const float* b_ih   = (const float*)d_in[4];
    const float* b_hh   = (const float*)d_in[5];
    const float* W_out  = (const float*)d_in[6];
    const float* b_out  = (const float*)d_in[7];

    char* w = (char*)d_ws;
    float* W_big = (float*)w; w += 3 * 64 * 64 * 4;            // 49152
    float* Wibn  = (float*)w; w += 4 * 64 * 4;                 // 1024
    float* cvec  = (float*)w; w += 256 * 4;                    // 1024
    float* W_T   = (float*)w; w += 302 * 192 * 4;              // 231936
    float* gi4   = (float*)w; w += (size_t)T_TOT * 256 * 4;    // 67108864
    float* h_all = (float*)w; w += (size_t)T_TOT * 64 * 4;     // 16777216

    hipLaunchKernelGGL(prep_kernel, dim3(277), dim3(256), 0, stream,
                       W_ih, W_hh, b_ih, b_hh, W_out, b_out, W_big, Wibn, cvec, W_T);
    hipLaunchKernelGGL(gi_gemm, dim3(T_TOT / 8), dim3(192), 0, stream,
                       neural, W_T, cvec, gi4);
    hipLaunchKernelGGL(gru_warm, dim3(1), dim3(64), 0, stream,
                       W_ih, W_hh, b_hh, b_gt, b_out, gi4, h_all);
    hipLaunchKernelGGL(gru_main, dim3(1), dim3(64), 0, stream,
                       W_big, Wibn, W_out, b_hh, gi4, h_all);
    hipLaunchKernelGGL(readout, dim3(T_TOT / 256), dim3(256), 0, stream,
                       h_all, W_out, b_out, (float*)d_out);
}

// Round 2
// 35285.117 us; speedup vs baseline: 1.1783x; 1.1783x over previous
//
#include <hip/hip_runtime.h>
#include <hip/hip_bf16.h>

#define T_TOT 65536
#define DN 302
#define DIN 306
#define L2E 1.4426950408889634f
#define S2E 2.8853900817779268f

typedef float v2f __attribute__((ext_vector_type(2)));
typedef float v4f __attribute__((ext_vector_type(4)));

// ---------------------------------------------------------------------------
// prep: build merged/scaled weights + transposed input GEMM weight
// ---------------------------------------------------------------------------
__global__ void prep_kernel(const float* __restrict__ W_ih, const float* __restrict__ W_hh,
                            const float* __restrict__ b_ih, const float* __restrict__ b_hh,
                            const float* __restrict__ W_out, const float* __restrict__ b_out,
                            float* __restrict__ W_big, float* __restrict__ Wibn,
                            float* __restrict__ cvec, float* __restrict__ W_T)
{
    int idx = blockIdx.x * 256 + threadIdx.x;
    if (idx < 12288) {
        int g = idx >> 12;
        int j = (idx >> 6) & 63;
        int l = idx & 63;
        float v;
        if (g < 2) {
            int i = g * 64 + l;
            float acc = W_hh[i * 64 + j];
            #pragma unroll
            for (int k = 0; k < 4; k++)
                acc = fmaf(W_ih[i * DIN + DN + k], W_out[k * 64 + j], acc);
            v = L2E * acc;
        } else {
            int i = 128 + l;
            v = S2E * W_hh[i * 64 + j];
        }
        W_big[idx] = v;
    } else if (idx < 12544) {
        int r = idx - 12288;
        int k = r >> 6, l = r & 63;
        Wibn[r] = S2E * W_ih[(128 + l) * DIN + DN + k];
    } else if (idx < 12736) {
        int i = idx - 12544;
        float acc = b_ih[i] + (i < 128 ? b_hh[i] : 0.f);
        #pragma unroll
        for (int k = 0; k < 4; k++)
            acc = fmaf(W_ih[i * DIN + DN + k], b_out[k], acc);
        cvec[i] = ((i < 128) ? L2E : S2E) * acc;
    } else if (idx < 12736 + 57984) {
        int r = idx - 12736;
        int k = r / 192;
        int c = r - k * 192;
        W_T[r] = W_ih[c * DIN + k];
    }
}

// ---------------------------------------------------------------------------
// A: gi4[t][l][{r,z,n,pad}] = scale * (W_ihn @ neural_t) + cvec
// ---------------------------------------------------------------------------
__global__ void gi_gemm(const float* __restrict__ neural, const float* __restrict__ W_T,
                        const float* __restrict__ cvec, float* __restrict__ gi4)
{
    int c = threadIdx.x;
    size_t t0 = (size_t)blockIdx.x * 8;
    float acc[8];
    #pragma unroll
    for (int q = 0; q < 8; q++) acc[q] = 0.f;
    const float* nptr = neural + t0 * DN;
    for (int k = 0; k < DN; k++) {
        float w = W_T[k * 192 + c];
        #pragma unroll
        for (int q = 0; q < 8; q++)
            acc[q] = fmaf(w, nptr[(size_t)q * DN + k], acc[q]);
    }
    float s  = (c < 128) ? L2E : S2E;
    float cv = cvec[c];
    int lo = c & 63, g = c >> 6;
    #pragma unroll
    for (int q = 0; q < 8; q++)
        gi4[(t0 + q) * 256 + lo * 4 + g] = fmaf(s, acc[q], cv);
}

// ---------------------------------------------------------------------------
// B: warmup steps t = 0,1,2 (GT feedback)
// ---------------------------------------------------------------------------
__global__ void gru_warm(const float* __restrict__ W_ih, const float* __restrict__ W_hh,
                         const float* __restrict__ b_hh, const float* __restrict__ b_gt,
                         const float* __restrict__ b_out, const float* __restrict__ gi4,
                         float* __restrict__ h_all)
{
    int l = threadIdx.x;
    __shared__ __align__(16) float hs[64];
    float wibr[4], wibz[4], wibn[4];
    #pragma unroll
    for (int k = 0; k < 4; k++) {
        wibr[k] = W_ih[l * DIN + DN + k];
        wibz[k] = W_ih[(64 + l) * DIN + DN + k];
        wibn[k] = W_ih[(128 + l) * DIN + DN + k];
    }
    float bhn = b_hh[128 + l];
    float h = 0.f;
    hs[l] = 0.f;
    for (int t = 0; t < 3; t++) {
        const float* bin = (t < 2) ? b_gt : (b_gt + 4);
        v4f g = *(const v4f*)(gi4 + (size_t)t * 256 + l * 4);
        float dr = 0.f, dz = 0.f, dn = 0.f;
        #pragma unroll
        for (int k = 0; k < 4; k++) {
            float d = bin[k] - b_out[k];
            dr = fmaf(wibr[k], d, dr);
            dz = fmaf(wibz[k], d, dz);
            dn = fmaf(wibn[k], d, dn);
        }
        float ur = g.x + L2E * dr, uz = g.y + L2E * dz, un_i = g.z + S2E * dn;
        float ar = 0.f, az = 0.f, anh = bhn;
        for (int j = 0; j < 64; j++) {
            float hj = hs[j];
            ar  = fmaf(W_hh[l * 64 + j],         hj, ar);
            az  = fmaf(W_hh[(64 + l) * 64 + j],  hj, az);
            anh = fmaf(W_hh[(128 + l) * 64 + j], hj, anh);
        }
        ur += L2E * ar;
        uz += L2E * az;
        float r = __builtin_amdgcn_rcpf(1.f + __builtin_amdgcn_exp2f(-ur));
        float z = __builtin_amdgcn_rcpf(1.f + __builtin_amdgcn_exp2f(-uz));
        float un = fmaf(r, S2E * anh, un_i);
        float e2 = __builtin_amdgcn_exp2f(un);
        float nn = fmaf(-2.f, __builtin_amdgcn_rcpf(e2 + 1.f), 1.f);
        h = nn + z * (h - nn);
        h_all[(size_t)t * 64 + l] = h;
        hs[l] = h;
    }
}

// ---------------------------------------------------------------------------
// DPP wave-reduce helpers: sum over all 64 lanes, result in every lane.
// 4 VALU DPP stages (intra-row-16) + ds_swizzle xor16 + shfl xor32.
// ---------------------------------------------------------------------------
template<int CTRL>
__device__ __forceinline__ float dppadd(float x) {
    int t = __builtin_amdgcn_update_dpp(0, __builtin_bit_cast(int, x), CTRL, 0xf, 0xf, false);
    return x + __builtin_bit_cast(float, t);
}
__device__ __forceinline__ float allred(float x) {
    x = dppadd<0xB1>(x);    // quad_perm [1,0,3,2]  (xor 1)
    x = dppadd<0x4E>(x);    // quad_perm [2,3,0,1]  (xor 2)
    x = dppadd<0x141>(x);   // row_half_mirror      (xor within 8)
    x = dppadd<0x140>(x);   // row_mirror           (xor within 16)
    x += __builtin_bit_cast(float, __builtin_amdgcn_ds_swizzle(__builtin_bit_cast(int, x), 0x401F)); // xor 16
    x += __shfl_xor(x, 32, 64);                                                                      // xor 32
    return x;
}

#define PIN8(a,b) asm volatile("" : "+v"(a[b]),"+v"(a[b+1]),"+v"(a[b+2]),"+v"(a[b+3]), \
                                    "+v"(a[b+4]),"+v"(a[b+5]),"+v"(a[b+6]),"+v"(a[b+7]))
#define PINALL \
    PIN8(wr,0); PIN8(wr,8); PIN8(wr,16); PIN8(wr,24); \
    PIN8(wz,0); PIN8(wz,8); PIN8(wz,16); PIN8(wz,24); \
    PIN8(wn,0); PIN8(wn,8); PIN8(wn,16); PIN8(wn,24)

// ---------------------------------------------------------------------------
// C: main sequential recurrence, t = 3..65535, single wave
// ---------------------------------------------------------------------------
__global__ __launch_bounds__(64, 1) void gru_main(
    const float* __restrict__ W_big, const float* __restrict__ Wibn,
    const float* __restrict__ W_out, const float* __restrict__ b_hh,
    const float* __restrict__ gi4, float* __restrict__ h_all)
{
    const int l = threadIdx.x;
    __shared__ __align__(16) float hs[64];

    v2f wr[32], wz[32], wn[32];
    #pragma unroll
    for (int j = 0; j < 32; j++) {
        wr[j] = v2f{W_big[(2 * j) * 64 + l],       W_big[(2 * j + 1) * 64 + l]};
        wz[j] = v2f{W_big[(64 + 2 * j) * 64 + l],  W_big[(64 + 2 * j + 1) * 64 + l]};
        wn[j] = v2f{W_big[(128 + 2 * j) * 64 + l], W_big[(128 + 2 * j + 1) * 64 + l]};
    }
    float wib0 = Wibn[l], wib1 = Wibn[64 + l], wib2 = Wibn[128 + l], wib3 = Wibn[192 + l];
    float wo0 = W_out[l], wo1 = W_out[64 + l], wo2 = W_out[128 + l], wo3 = W_out[192 + l];
    const float bhn_s = S2E * b_hh[128 + l];

    float h = h_all[2 * 64 + l];
    hs[l] = h;

    float corr;
    {
        float y0 = allred(wo0 * h);
        float y1 = allred(wo1 * h);
        float y2 = allred(wo2 * h);
        float y3 = allred(wo3 * h);
        corr = fmaf(wib3, y3, fmaf(wib2, y2, fmaf(wib1, y1, wib0 * y0)));
    }

    auto step = [&](v4f g, float* hstore) {
        v2f ar0 = v2f{0.f, 0.f}, ar1 = v2f{0.f, 0.f};
        v2f az0 = v2f{0.f, 0.f}, az1 = v2f{0.f, 0.f};
        v2f an0 = v2f{bhn_s, 0.f}, an1 = v2f{0.f, 0.f};
        #pragma unroll
        for (int jc = 0; jc < 16; jc++) {
            v4f hv = *(const v4f*)(hs + 4 * jc);
            v2f h01 = v2f{hv.x, hv.y}, h23 = v2f{hv.z, hv.w};
            ar0 = __builtin_elementwise_fma(wr[2 * jc],     h01, ar0);
            ar1 = __builtin_elementwise_fma(wr[2 * jc + 1], h23, ar1);
            az0 = __builtin_elementwise_fma(wz[2 * jc],     h01, az0);
            az1 = __builtin_elementwise_fma(wz[2 * jc + 1], h23, az1);
            an0 = __builtin_elementwise_fma(wn[2 * jc],     h01, an0);
            an1 = __builtin_elementwise_fma(wn[2 * jc + 1], h23, an1);
        }
        v2f ars = ar0 + ar1, azs = az0 + az1, ans = an0 + an1;
        float ar = ars.x + ars.y, az = azs.x + azs.y, an = ans.x + ans.y;
        float ur = g.x + ar, uz = g.y + az;
        float r = __builtin_amdgcn_rcpf(1.f + __builtin_amdgcn_exp2f(-ur));
        float z = __builtin_amdgcn_rcpf(1.f + __builtin_amdgcn_exp2f(-uz));
        float un = g.z + corr + r * an;
        float e2 = __builtin_amdgcn_exp2f(un);
        float nn = fmaf(-2.f, __builtin_amdgcn_rcpf(e2 + 1.f), 1.f);
        h = nn + z * (h - nn);
        *hstore = h;
        hs[l] = h;      // single wave, in-order LDS: reads above already done
        float y0 = allred(wo0 * h);
        float y1 = allred(wo1 * h);
        float y2 = allred(wo2 * h);
        float y3 = allred(wo3 * h);
        corr = fmaf(wib3, y3, fmaf(wib2, y2, fmaf(wib1, y1, wib0 * y0)));
    };

    const v4f* gp = (const v4f*)gi4;
    v4f gA = gp[(size_t)3 * 64 + l];
    v4f gB = gp[(size_t)4 * 64 + l];
    const v4f* pf = gp + (size_t)5 * 64 + l;
    float* hp = h_all + (size_t)3 * 64 + l;

    for (int t = 3; t + 1 < T_TOT; t += 2) {
        v4f gC = pf[0];      // t+2
        v4f gD = pf[64];     // t+3 (last iter overreads 1 row into h_all: benign)
        pf += 128;
        PINALL;
        step(gA, hp);
        step(gB, hp + 64);
        hp += 128;
        gA = gC;
        gB = gD;
    }
    step(gA, hp);            // t = 65535
}

// ---------------------------------------------------------------------------
// D: preds = h_all @ W_out^T + b_out
// ---------------------------------------------------------------------------
__global__ void readout(const float* __restrict__ h_all, const float* __restrict__ W_out,
                        const float* __restrict__ b_out, float* __restrict__ preds)
{
    int t = blockIdx.x * 256 + threadIdx.x;
    v4f acc = v4f{b_out[0], b_out[1], b_out[2], b_out[3]};
    const v4f* hp = (const v4f*)(h_all + (size_t)t * 64);
    #pragma unroll
    for (int jc = 0; jc < 16; jc++) {
        v4f hv = hp[jc];
        #pragma unroll
        for (int e = 0; e < 4; e++) {
            float hvv = hv[e];
            int j = jc * 4 + e;
            acc.x = fmaf(W_out[j],       hvv, acc.x);
            acc.y = fmaf(W_out[64 + j],  hvv, acc.y);
            acc.z = fmaf(W_out[128 + j], hvv, acc.z);
            acc.w = fmaf(W_out[192 + j], hvv, acc.w);
        }
    }
    *(v4f*)(preds + (size_t)t * 4) = acc;
}

// ---------------------------------------------------------------------------
extern "C" void kernel_launch(void* const* d_in, const int* in_sizes, int n_in,
                              void* d_out, int out_size, void* d_ws, size_t ws_size,
                              hipStream_t stream)
{
    const float* neural = (const float*)d_in[0];
    const float* b_gt   = (const float*)d_in[1];
    const float* W_ih   = (const float*)d_in[2];
    const float* W_hh   = (const float*)d_in[3];
    const float* b_ih   = (const float*)d_in[4];
    const float* b_hh   = (const float*)d_in[5];
    const float* W_out  = (const float*)d_in[6];
    const float* b_out  = (const float*)d_in[7];

    char* w = (char*)d_ws;
    float* W_big = (float*)w; w += 3 * 64 * 64 * 4;
    float* Wibn  = (float*)w; w += 4 * 64 * 4;
    float* cvec  = (float*)w; w += 256 * 4;
    float* W_T   = (float*)w; w += 302 * 192 * 4;
    float* gi4   = (float*)w; w += (size_t)T_TOT * 256 * 4;
    float* h_all = (float*)w; w += (size_t)T_TOT * 64 * 4;

    hipLaunchKernelGGL(prep_kernel, dim3(277), dim3(256), 0, stream,
                       W_ih, W_hh, b_ih, b_hh, W_out, b_out, W_big, Wibn, cvec, W_T);
    hipLaunchKernelGGL(gi_gemm, dim3(T_TOT / 8), dim3(192), 0, stream,
                       neural, W_T, cvec, gi4);
    hipLaunchKernelGGL(gru_warm, dim3(1), dim3(64), 0, stream,
                       W_ih, W_hh, b_hh, b_gt, b_out, gi4, h_all);
    hipLaunchKernelGGL(gru_main, dim3(1), dim3(64), 0, stream,
                       W_big, Wibn, W_out, b_hh, gi4, h_all);
    hipLaunchKernelGGL(readout, dim3(T_TOT / 256), dim3(256), 0, stream,
                       h_all, W_out, b_out, (float*)d_out);
}